// Round 2
// baseline (388.759 us; speedup 1.0000x reference)
//
#include <hip/hip_runtime.h>

typedef __bf16 bf16;
using bf16x2 = __attribute__((ext_vector_type(2))) bf16;
using bf16x4 = __attribute__((ext_vector_type(4))) bf16;
using bf16x8 = __attribute__((ext_vector_type(8))) bf16;
using f32x4  = __attribute__((ext_vector_type(4))) float;

#define DEVI __device__ __forceinline__

DEVI void gload_lds16(const void* g, void* l) {
  __builtin_amdgcn_global_load_lds((const __attribute__((address_space(1))) void*)g,
                                   (__attribute__((address_space(3))) void*)l, 16, 0, 0);
}

// ---------------- fp32 -> bf16 convert (4 elems/thread, exact grids) ------
__global__ __launch_bounds__(256) void k_cvt(const float* __restrict__ in,
                                             bf16* __restrict__ out) {
  int i = blockIdx.x * 256 + threadIdx.x;
  f32x4 v = ((const f32x4*)in)[i];
  bf16x4 o = {(bf16)v.x, (bf16)v.y, (bf16)v.z, (bf16)v.w};
  ((bf16x4*)out)[i] = o;
}

// ---------------- GEMM: out[m,n] = sum_k A[m,k]*W[n,k] (+bias) ------------
// 128x128 tile, BK=32, 4 waves (2x2 of 64x64), global_load_lds width=16.
template<int OUT_BF16, int HAS_BIAS>
__global__ __launch_bounds__(256) void k_gemm_bt(
    const bf16* __restrict__ A, const bf16* __restrict__ W,
    const float* __restrict__ bias, void* __restrict__ outp,
    int Kk, int Nout)
{
  __shared__ __align__(16) bf16 As[128 * 32];
  __shared__ __align__(16) bf16 Bs[128 * 32];
  const int t = threadIdx.x;
  const int lane = t & 63, wv = t >> 6;
  const int l15 = lane & 15, l4 = lane >> 4;
  const int row0 = blockIdx.x * 128, col0 = blockIdx.y * 128;
  const int wr = wv >> 1, wc = wv & 1;

  f32x4 acc[4][4];
  #pragma unroll
  for (int m = 0; m < 4; ++m)
    #pragma unroll
    for (int n = 0; n < 4; ++n) acc[m][n] = (f32x4){0.f, 0.f, 0.f, 0.f};

  // staging: 512 chunks of 16B per 128x32 tile; thread t owns chunks t, t+256
  const int g0 = t, g1 = t + 256;
  const bf16* ga0 = A + (size_t)(row0 + (g0 >> 2)) * Kk + (g0 & 3) * 8;
  const bf16* ga1 = A + (size_t)(row0 + (g1 >> 2)) * Kk + (g1 & 3) * 8;
  const bf16* gb0 = W + (size_t)(col0 + (g0 >> 2)) * Kk + (g0 & 3) * 8;
  const bf16* gb1 = W + (size_t)(col0 + (g1 >> 2)) * Kk + (g1 & 3) * 8;
  // wave-uniform LDS bases (lane*16 is added by HW)
  char* la0 = (char*)As + wv * 1024;
  char* la1 = (char*)As + 4096 + wv * 1024;
  char* lb0 = (char*)Bs + wv * 1024;
  char* lb1 = (char*)Bs + 4096 + wv * 1024;

  const int nk = Kk >> 5;
  for (int kt = 0; kt < nk; ++kt) {
    __syncthreads();
    gload_lds16(ga0 + kt * 32, la0);
    gload_lds16(ga1 + kt * 32, la1);
    gload_lds16(gb0 + kt * 32, lb0);
    gload_lds16(gb1 + kt * 32, lb1);
    __syncthreads();
    bf16x8 af[4], bfv[4];
    #pragma unroll
    for (int m = 0; m < 4; ++m)
      af[m] = *(const bf16x8*)(As + (wr * 64 + m * 16 + l15) * 32 + l4 * 8);
    #pragma unroll
    for (int n = 0; n < 4; ++n)
      bfv[n] = *(const bf16x8*)(Bs + (wc * 64 + n * 16 + l15) * 32 + l4 * 8);
    #pragma unroll
    for (int m = 0; m < 4; ++m)
      #pragma unroll
      for (int n = 0; n < 4; ++n)
        acc[m][n] = __builtin_amdgcn_mfma_f32_16x16x32_bf16(af[m], bfv[n], acc[m][n], 0, 0, 0);
  }

  // epilogue: D[row=(l>>4)*4+r][col=l&15] (m89-verified mapping)
  #pragma unroll
  for (int n = 0; n < 4; ++n) {
    const int col = col0 + wc * 64 + n * 16 + l15;
    float bv = HAS_BIAS ? bias[col] : 0.f;
    #pragma unroll
    for (int m = 0; m < 4; ++m) {
      #pragma unroll
      for (int r = 0; r < 4; ++r) {
        const int row = row0 + wr * 64 + m * 16 + l4 * 4 + r;
        float v = acc[m][n][r] + bv;
        if (OUT_BF16) ((bf16*)outp)[(size_t)row * Nout + col] = (bf16)v;
        else          ((float*)outp)[(size_t)row * Nout + col] = v;
      }
    }
  }
}

// ---------------- per-row L2 norm of q and k (one wave per row) -----------
__global__ __launch_bounds__(256) void k_rownorm(const bf16* __restrict__ qkv,
                                                 float* __restrict__ invq,
                                                 float* __restrict__ invk)
{
  const int row = blockIdx.x * 4 + (threadIdx.x >> 6);
  const int lane = threadIdx.x & 63;
  const bf16* p = qkv + (size_t)row * 3072 + lane * 16;
  float sq = 0.f, sk = 0.f;
  bf16x8 a0 = *(const bf16x8*)(p);
  bf16x8 a1 = *(const bf16x8*)(p + 8);
  bf16x8 b0 = *(const bf16x8*)(p + 1024);
  bf16x8 b1 = *(const bf16x8*)(p + 1032);
  #pragma unroll
  for (int j = 0; j < 8; ++j) {
    float x0 = (float)a0[j], x1 = (float)a1[j];
    float y0 = (float)b0[j], y1 = (float)b1[j];
    sq += x0 * x0 + x1 * x1;
    sk += y0 * y0 + y1 * y1;
  }
  #pragma unroll
  for (int m = 1; m <= 32; m <<= 1) {
    sq += __shfl_xor(sq, m);
    sk += __shfl_xor(sk, m);
  }
  if (lane == 0) {
    invq[row] = 0.125f / fmaxf(sqrtf(sq), 1e-12f);   // scale/max(||q||,eps)
    invk[row] = 0.125f / fmaxf(sqrtf(sk), 1e-12f);
  }
}

// ---------------- head split + normalize + V transpose --------------------
// Qh,Kh: [B,H,N,64] (normalized*0.125);  Vt: [B,H,64,N]
__global__ __launch_bounds__(256) void k_scatter(
    const bf16* __restrict__ qkv, const float* __restrict__ invq,
    const float* __restrict__ invk,
    bf16* __restrict__ Qh, bf16* __restrict__ Kh, bf16* __restrict__ Vt)
{
  __shared__ __align__(16) bf16 vt[64][72];
  const int t = threadIdx.x;
  const int b = blockIdx.z, h = blockIdx.y;
  const int n0 = blockIdx.x * 64;
  {
    const int nl = t >> 2;
    const int d0 = (t & 3) << 4;
    const size_t row = (size_t)b * 2048 + n0 + nl;
    const bf16* src = qkv + row * 3072 + h * 64 + d0;
    const float fq = invq[row];
    const float fk = invk[row];
    bf16x8 q0 = *(const bf16x8*)(src);
    bf16x8 q1 = *(const bf16x8*)(src + 8);
    bf16x8 k0 = *(const bf16x8*)(src + 1024);
    bf16x8 k1 = *(const bf16x8*)(src + 1032);
    bf16x8 v0 = *(const bf16x8*)(src + 2048);
    bf16x8 v1 = *(const bf16x8*)(src + 2056);
    bf16x8 qo, ko;
    #pragma unroll
    for (int j = 0; j < 8; ++j) {
      qo[j] = (bf16)((float)q0[j] * fq);
      ko[j] = (bf16)((float)k0[j] * fk);
    }
    size_t orow = ((size_t)(b * 16 + h) * 2048 + n0 + nl) * 64 + d0;
    *(bf16x8*)(Qh + orow) = qo;
    *(bf16x8*)(Kh + orow) = ko;
    #pragma unroll
    for (int j = 0; j < 8; ++j) {
      qo[j] = (bf16)((float)q1[j] * fq);
      ko[j] = (bf16)((float)k1[j] * fk);
    }
    *(bf16x8*)(Qh + orow + 8) = qo;
    *(bf16x8*)(Kh + orow + 8) = ko;
    *(bf16x8*)&vt[nl][d0] = v0;
    *(bf16x8*)&vt[nl][d0 + 8] = v1;
  }
  __syncthreads();
  {
    const int d = t >> 2;
    const int nc = (t & 3) << 4;
    bf16x8 o0, o1;
    #pragma unroll
    for (int j = 0; j < 8; ++j) { o0[j] = vt[nc + j][d]; o1[j] = vt[nc + 8 + j][d]; }
    size_t obase = ((size_t)(b * 16 + h) * 64 + d) * 2048 + n0 + nc;
    *(bf16x8*)(Vt + obase) = o0;
    *(bf16x8*)(Vt + obase + 8) = o1;
  }
}

// ---------------- flash attention ----------------------------------------
// Block: 4 waves x 16 q-rows (QT=64), KV tile 64, full softmax over N=2048.
// Swapped QK^T: mfma(K,Q) -> lane holds S[q=l&15][kv=(l>>4)*4+r] so the
// row-reduce is 2x shfl_xor. P goes through padded per-wave LDS into
// A-fragment layout for PV; V is consumed from Vt [D][N] (16B rows, L2-hot).
__global__ __launch_bounds__(256) void k_attn(
    const bf16* __restrict__ Qh, const bf16* __restrict__ Kh,
    const bf16* __restrict__ Vt, const float* __restrict__ temperature,
    bf16* __restrict__ ao)
{
  __shared__ __align__(16) bf16 Plds[4][16][72];
  const int t = threadIdx.x, lane = t & 63, wv = t >> 6;
  const int l15 = lane & 15, l4 = lane >> 4;
  const int b = blockIdx.z, h = blockIdx.y;
  const int q0 = blockIdx.x * 64 + wv * 16;
  const float invT = 1.f / temperature[h];
  const size_t plane = (size_t)(b * 16 + h) * (2048 * 64);
  const bf16* Qp = Qh + plane;
  const bf16* Kp = Kh + plane;
  const bf16* Vp = Vt + plane;
  bf16* pl = &Plds[wv][0][0];

  bf16x8 qf0 = *(const bf16x8*)(Qp + (q0 + l15) * 64 + l4 * 8);
  bf16x8 qf1 = *(const bf16x8*)(Qp + (q0 + l15) * 64 + 32 + l4 * 8);

  f32x4 accO[4];
  #pragma unroll
  for (int df = 0; df < 4; ++df) accO[df] = (f32x4){0.f, 0.f, 0.f, 0.f};
  float mrun = -__builtin_inff(), lrun = 0.f;

  for (int kt = 0; kt < 32; ++kt) {
    const int kv0 = kt * 64;
    f32x4 s[4];
    #pragma unroll
    for (int kvf = 0; kvf < 4; ++kvf) {
      s[kvf] = (f32x4){0.f, 0.f, 0.f, 0.f};
      const bf16* kp = Kp + (size_t)(kv0 + kvf * 16 + l15) * 64 + l4 * 8;
      bf16x8 kf0 = *(const bf16x8*)(kp);
      bf16x8 kf1 = *(const bf16x8*)(kp + 32);
      s[kvf] = __builtin_amdgcn_mfma_f32_16x16x32_bf16(kf0, qf0, s[kvf], 0, 0, 0);
      s[kvf] = __builtin_amdgcn_mfma_f32_16x16x32_bf16(kf1, qf1, s[kvf], 0, 0, 0);
    }
    float p[4][4];
    float tm = -__builtin_inff();
    #pragma unroll
    for (int kvf = 0; kvf < 4; ++kvf)
      #pragma unroll
      for (int r = 0; r < 4; ++r) {
        p[kvf][r] = s[kvf][r] * invT;
        tm = fmaxf(tm, p[kvf][r]);
      }
    tm = fmaxf(tm, __shfl_xor(tm, 16));
    tm = fmaxf(tm, __shfl_xor(tm, 32));
    const float mnew = fmaxf(mrun, tm);
    const float alpha = __expf(mrun - mnew);
    float ts = 0.f;
    #pragma unroll
    for (int kvf = 0; kvf < 4; ++kvf)
      #pragma unroll
      for (int r = 0; r < 4; ++r) {
        p[kvf][r] = __expf(p[kvf][r] - mnew);
        ts += p[kvf][r];
      }
    ts += __shfl_xor(ts, 16);
    ts += __shfl_xor(ts, 32);
    lrun = lrun * alpha + ts;
    mrun = mnew;
    // P -> per-wave LDS, packed pairs (kv consecutive)
    #pragma unroll
    for (int kvf = 0; kvf < 4; ++kvf)
      #pragma unroll
      for (int rp = 0; rp < 2; ++rp) {
        bf16x2 pv = {(bf16)p[kvf][2 * rp], (bf16)p[kvf][2 * rp + 1]};
        *(bf16x2*)(pl + l15 * 72 + kvf * 16 + l4 * 4 + 2 * rp) = pv;
      }
    // rescale O (output rows live at q'=(l>>4)*4+r; alpha lives at lane&15=q')
    #pragma unroll
    for (int r = 0; r < 4; ++r) {
      const float ar = __shfl(alpha, (lane & 48) | (l4 * 4 + r));
      #pragma unroll
      for (int df = 0; df < 4; ++df) accO[df][r] *= ar;
    }
    // PV: A=P from LDS, B=V from Vt rows
    #pragma unroll
    for (int ss = 0; ss < 2; ++ss) {
      bf16x8 pf = *(const bf16x8*)(pl + l15 * 72 + ss * 32 + l4 * 8);
      #pragma unroll
      for (int df = 0; df < 4; ++df) {
        bf16x8 vf = *(const bf16x8*)(Vp + (size_t)(df * 16 + l15) * 2048 + kv0 + ss * 32 + l4 * 8);
        accO[df] = __builtin_amdgcn_mfma_f32_16x16x32_bf16(pf, vf, accO[df], 0, 0, 0);
      }
    }
  }
  // finalize: divide by lrun (per output row), write [B,N,H*64] bf16
  #pragma unroll
  for (int r = 0; r < 4; ++r) {
    const int qq = l4 * 4 + r;
    const float lr = __shfl(lrun, (lane & 48) | qq);
    const float inv = 1.f / lr;
    const size_t orow = ((size_t)b * 2048 + q0 + qq) * 1024 + h * 64;
    #pragma unroll
    for (int df = 0; df < 4; ++df)
      ao[orow + df * 16 + l15] = (bf16)(accO[df][r] * inv);
  }
}

// --------------------------------------------------------------------------
extern "C" void kernel_launch(void* const* d_in, const int* in_sizes, int n_in,
                              void* d_out, int out_size, void* d_ws, size_t ws_size,
                              hipStream_t stream)
{
  (void)in_sizes; (void)n_in; (void)out_size; (void)ws_size;
  const float* x      = (const float*)d_in[0];   // [2,2048,1024]
  const float* qkv_w  = (const float*)d_in[1];   // [3072,1024]
  const float* temp   = (const float*)d_in[2];   // [16,1,1]
  const float* proj_w = (const float*)d_in[3];   // [1024,1024]
  const float* proj_b = (const float*)d_in[4];   // [1024]
  float* out = (float*)d_out;                    // [2,2048,1024] fp32

  char* w = (char*)d_ws;
  auto take = [&](size_t bytes) { char* p = w; w += (bytes + 255) & ~(size_t)255; return p; };
  bf16*  xb    = (bf16*)take((size_t)4096 * 1024 * 2);   // x bf16
  bf16*  wqkvb = (bf16*)take((size_t)3072 * 1024 * 2);   // qkv_w bf16
  bf16*  wpb   = (bf16*)take((size_t)1024 * 1024 * 2);   // proj_w bf16
  bf16*  qkvb  = (bf16*)take((size_t)4096 * 3072 * 2);   // qkv out bf16
  float* invq  = (float*)take((size_t)4096 * 4);
  float* invk  = (float*)take((size_t)4096 * 4);
  bf16*  Qh    = (bf16*)take((size_t)32 * 2048 * 64 * 2);
  bf16*  Kh    = (bf16*)take((size_t)32 * 2048 * 64 * 2);
  bf16*  Vt    = (bf16*)take((size_t)32 * 64 * 2048 * 2);
  bf16*  ao    = (bf16*)take((size_t)4096 * 1024 * 2);

  k_cvt<<<4096, 256, 0, stream>>>(x, xb);
  k_cvt<<<3072, 256, 0, stream>>>(qkv_w, wqkvb);
  k_cvt<<<1024, 256, 0, stream>>>(proj_w, wpb);
  k_gemm_bt<1, 0><<<dim3(32, 24), 256, 0, stream>>>(xb, wqkvb, nullptr, qkvb, 1024, 3072);
  k_rownorm<<<1024, 256, 0, stream>>>(qkvb, invq, invk);
  k_scatter<<<dim3(32, 16, 2), 256, 0, stream>>>(qkvb, invq, invk, Qh, Kh, Vt);
  k_attn<<<dim3(32, 16, 2), 256, 0, stream>>>(Qh, Kh, Vt, temp, ao);
  k_gemm_bt<0, 1><<<dim3(32, 8), 256, 0, stream>>>(ao, wpb, proj_b, out, 1024, 1024);
}

// Round 5
// 385.618 us; speedup vs baseline: 1.0081x; 1.0081x over previous
//
#include <hip/hip_runtime.h>

typedef __bf16 bf16;
using bf16x2 = __attribute__((ext_vector_type(2))) bf16;
using bf16x4 = __attribute__((ext_vector_type(4))) bf16;
using bf16x8 = __attribute__((ext_vector_type(8))) bf16;
using f32x4  = __attribute__((ext_vector_type(4))) float;

#define DEVI __device__ __forceinline__

DEVI void gload_lds16(const void* g, void* l) {
  __builtin_amdgcn_global_load_lds((const __attribute__((address_space(1))) void*)g,
                                   (__attribute__((address_space(3))) void*)l, 16, 0, 0);
}

DEVI float exp2_fast(float x) { return __builtin_amdgcn_exp2f(x); }  // v_exp_f32

// ---------------- fp32 -> bf16 convert (4 elems/thread, exact grids) ------
__global__ __launch_bounds__(256) void k_cvt(const float* __restrict__ in,
                                             bf16* __restrict__ out) {
  int i = blockIdx.x * 256 + threadIdx.x;
  f32x4 v = ((const f32x4*)in)[i];
  bf16x4 o = {(bf16)v.x, (bf16)v.y, (bf16)v.z, (bf16)v.w};
  ((bf16x4*)out)[i] = o;
}

// ---------------- GEMM: out[m,n] = sum_k A[m,k]*W[n,k] (+bias) ------------
// 128x128 tile, BK=32, 4 waves (2x2 of 64x64), global_load_lds width=16.
template<int OUT_BF16, int HAS_BIAS>
__global__ __launch_bounds__(256) void k_gemm_bt(
    const bf16* __restrict__ A, const bf16* __restrict__ W,
    const float* __restrict__ bias, void* __restrict__ outp,
    int Kk, int Nout)
{
  __shared__ __align__(16) bf16 As[128 * 32];
  __shared__ __align__(16) bf16 Bs[128 * 32];
  const int t = threadIdx.x;
  const int lane = t & 63, wv = t >> 6;
  const int l15 = lane & 15, l4 = lane >> 4;
  const int row0 = blockIdx.x * 128, col0 = blockIdx.y * 128;
  const int wr = wv >> 1, wc = wv & 1;

  f32x4 acc[4][4];
  #pragma unroll
  for (int m = 0; m < 4; ++m)
    #pragma unroll
    for (int n = 0; n < 4; ++n) acc[m][n] = (f32x4){0.f, 0.f, 0.f, 0.f};

  // staging: 512 chunks of 16B per 128x32 tile; thread t owns chunks t, t+256
  const int g0 = t, g1 = t + 256;
  const bf16* ga0 = A + (size_t)(row0 + (g0 >> 2)) * Kk + (g0 & 3) * 8;
  const bf16* ga1 = A + (size_t)(row0 + (g1 >> 2)) * Kk + (g1 & 3) * 8;
  const bf16* gb0 = W + (size_t)(col0 + (g0 >> 2)) * Kk + (g0 & 3) * 8;
  const bf16* gb1 = W + (size_t)(col0 + (g1 >> 2)) * Kk + (g1 & 3) * 8;
  // wave-uniform LDS bases (lane*16 is added by HW)
  char* la0 = (char*)As + wv * 1024;
  char* la1 = (char*)As + 4096 + wv * 1024;
  char* lb0 = (char*)Bs + wv * 1024;
  char* lb1 = (char*)Bs + 4096 + wv * 1024;

  const int nk = Kk >> 5;
  for (int kt = 0; kt < nk; ++kt) {
    __syncthreads();
    gload_lds16(ga0 + kt * 32, la0);
    gload_lds16(ga1 + kt * 32, la1);
    gload_lds16(gb0 + kt * 32, lb0);
    gload_lds16(gb1 + kt * 32, lb1);
    __syncthreads();
    bf16x8 af[4], bfv[4];
    #pragma unroll
    for (int m = 0; m < 4; ++m)
      af[m] = *(const bf16x8*)(As + (wr * 64 + m * 16 + l15) * 32 + l4 * 8);
    #pragma unroll
    for (int n = 0; n < 4; ++n)
      bfv[n] = *(const bf16x8*)(Bs + (wc * 64 + n * 16 + l15) * 32 + l4 * 8);
    #pragma unroll
    for (int m = 0; m < 4; ++m)
      #pragma unroll
      for (int n = 0; n < 4; ++n)
        acc[m][n] = __builtin_amdgcn_mfma_f32_16x16x32_bf16(af[m], bfv[n], acc[m][n], 0, 0, 0);
  }

  // epilogue: D[row=(l>>4)*4+r][col=l&15] (m89-verified mapping)
  #pragma unroll
  for (int n = 0; n < 4; ++n) {
    const int col = col0 + wc * 64 + n * 16 + l15;
    float bv = HAS_BIAS ? bias[col] : 0.f;
    #pragma unroll
    for (int m = 0; m < 4; ++m) {
      #pragma unroll
      for (int r = 0; r < 4; ++r) {
        const int row = row0 + wr * 64 + m * 16 + l4 * 4 + r;
        float v = acc[m][n][r] + bv;
        if (OUT_BF16) ((bf16*)outp)[(size_t)row * Nout + col] = (bf16)v;
        else          ((float*)outp)[(size_t)row * Nout + col] = v;
      }
    }
  }
}

// ---------------- per-row L2 norm of q and k (one wave per row) -----------
__global__ __launch_bounds__(256) void k_rownorm(const bf16* __restrict__ qkv,
                                                 float* __restrict__ invq,
                                                 float* __restrict__ invk)
{
  const int row = blockIdx.x * 4 + (threadIdx.x >> 6);
  const int lane = threadIdx.x & 63;
  const bf16* p = qkv + (size_t)row * 3072 + lane * 16;
  float sq = 0.f, sk = 0.f;
  bf16x8 a0 = *(const bf16x8*)(p);
  bf16x8 a1 = *(const bf16x8*)(p + 8);
  bf16x8 b0 = *(const bf16x8*)(p + 1024);
  bf16x8 b1 = *(const bf16x8*)(p + 1032);
  #pragma unroll
  for (int j = 0; j < 8; ++j) {
    float x0 = (float)a0[j], x1 = (float)a1[j];
    float y0 = (float)b0[j], y1 = (float)b1[j];
    sq += x0 * x0 + x1 * x1;
    sk += y0 * y0 + y1 * y1;
  }
  #pragma unroll
  for (int m = 1; m <= 32; m <<= 1) {
    sq += __shfl_xor(sq, m);
    sk += __shfl_xor(sk, m);
  }
  if (lane == 0) {
    invq[row] = 0.125f / fmaxf(sqrtf(sq), 1e-12f);   // scale/max(||q||,eps)
    invk[row] = 0.125f / fmaxf(sqrtf(sk), 1e-12f);
  }
}

// ---------------- head split + normalize + V transpose --------------------
// Qh: [B,H,N,64] = q_hat*0.125
// Kh: [B,H,N,64] = k_hat*0.125*log2(e)/T[h]   (so QK^T is exp2-ready)
// Vt: [B,H,64,N]
__global__ __launch_bounds__(256) void k_scatter(
    const bf16* __restrict__ qkv, const float* __restrict__ invq,
    const float* __restrict__ invk, const float* __restrict__ temperature,
    bf16* __restrict__ Qh, bf16* __restrict__ Kh, bf16* __restrict__ Vt)
{
  __shared__ __align__(16) bf16 vt[64][72];
  const int t = threadIdx.x;
  const int b = blockIdx.z, h = blockIdx.y;
  const int n0 = blockIdx.x * 64;
  const float tfac = 1.4426950408889634f / temperature[h];  // log2(e)/T
  {
    const int nl = t >> 2;
    const int d0 = (t & 3) << 4;
    const size_t row = (size_t)b * 2048 + n0 + nl;
    const bf16* src = qkv + row * 3072 + h * 64 + d0;
    const float fq = invq[row];
    const float fk = invk[row] * tfac;
    bf16x8 q0 = *(const bf16x8*)(src);
    bf16x8 q1 = *(const bf16x8*)(src + 8);
    bf16x8 k0 = *(const bf16x8*)(src + 1024);
    bf16x8 k1 = *(const bf16x8*)(src + 1032);
    bf16x8 v0 = *(const bf16x8*)(src + 2048);
    bf16x8 v1 = *(const bf16x8*)(src + 2056);
    bf16x8 qo, ko;
    #pragma unroll
    for (int j = 0; j < 8; ++j) {
      qo[j] = (bf16)((float)q0[j] * fq);
      ko[j] = (bf16)((float)k0[j] * fk);
    }
    size_t orow = ((size_t)(b * 16 + h) * 2048 + n0 + nl) * 64 + d0;
    *(bf16x8*)(Qh + orow) = qo;
    *(bf16x8*)(Kh + orow) = ko;
    #pragma unroll
    for (int j = 0; j < 8; ++j) {
      qo[j] = (bf16)((float)q1[j] * fq);
      ko[j] = (bf16)((float)k1[j] * fk);
    }
    *(bf16x8*)(Qh + orow + 8) = qo;
    *(bf16x8*)(Kh + orow + 8) = ko;
    *(bf16x8*)&vt[nl][d0] = v0;
    *(bf16x8*)&vt[nl][d0 + 8] = v1;
  }
  __syncthreads();
  {
    const int d = t >> 2;
    const int nc = (t & 3) << 4;
    bf16x8 o0, o1;
    #pragma unroll
    for (int j = 0; j < 8; ++j) { o0[j] = vt[nc + j][d]; o1[j] = vt[nc + 8 + j][d]; }
    size_t obase = ((size_t)(b * 16 + h) * 64 + d) * 2048 + n0 + nc;
    *(bf16x8*)(Vt + obase) = o0;
    *(bf16x8*)(Vt + obase + 8) = o1;
  }
}

// ---------------- flash attention, max-free softmax -----------------------
// |S| <= 1/64 * log2e / T by construction (q,k unit-normalized, 0.125 each,
// log2e/T folded into K), so exp2(S) in [0.98, 1.02]: no running max, no
// rescale, no cross-iteration serial chain. Denominator = extra MFMA vs an
// all-ones B fragment (accumulates row-sums of bf16-quantized P, consistent
// with the numerator). Swapped QK^T: mfma(K,Q) -> S[kv][q=l15]; P goes via
// padded per-wave LDS (in-order per-wave LDS pipe makes write->read safe)
// into A-fragment layout for PV. V consumed from Vt [D][N] rows.
__global__ __launch_bounds__(256) void k_attn(
    const bf16* __restrict__ Qh, const bf16* __restrict__ Kh,
    const bf16* __restrict__ Vt, bf16* __restrict__ ao)
{
  __shared__ __align__(16) bf16 Plds[4][16][72];
  const int t = threadIdx.x, lane = t & 63, wv = t >> 6;
  const int l15 = lane & 15, l4 = lane >> 4;
  const int b = blockIdx.z, h = blockIdx.y;
  const int q0 = blockIdx.x * 64 + wv * 16;
  const size_t plane = (size_t)(b * 16 + h) * (2048 * 64);
  const bf16* Qp = Qh + plane;
  const bf16* Kp = Kh + plane;
  const bf16* Vp = Vt + plane;
  bf16* pl = &Plds[wv][0][0];

  bf16x8 qf0 = *(const bf16x8*)(Qp + (q0 + l15) * 64 + l4 * 8);
  bf16x8 qf1 = *(const bf16x8*)(Qp + (q0 + l15) * 64 + 32 + l4 * 8);

  bf16x8 vones;
  #pragma unroll
  for (int j = 0; j < 8; ++j) vones[j] = (bf16)1.0f;

  f32x4 accO[4];
  #pragma unroll
  for (int df = 0; df < 4; ++df) accO[df] = (f32x4){0.f, 0.f, 0.f, 0.f};
  f32x4 accS = (f32x4){0.f, 0.f, 0.f, 0.f};

  for (int kt = 0; kt < 32; ++kt) {
    const int kv0 = kt * 64;
    f32x4 s[4];
    #pragma unroll
    for (int kvf = 0; kvf < 4; ++kvf) {
      s[kvf] = (f32x4){0.f, 0.f, 0.f, 0.f};
      const bf16* kp = Kp + (size_t)(kv0 + kvf * 16 + l15) * 64 + l4 * 8;
      bf16x8 kf0 = *(const bf16x8*)(kp);
      bf16x8 kf1 = *(const bf16x8*)(kp + 32);
      s[kvf] = __builtin_amdgcn_mfma_f32_16x16x32_bf16(kf0, qf0, s[kvf], 0, 0, 0);
      s[kvf] = __builtin_amdgcn_mfma_f32_16x16x32_bf16(kf1, qf1, s[kvf], 0, 0, 0);
    }
    // P = exp2(S) -> bf16 pairs -> per-wave LDS (same-wave in-order pipe)
    #pragma unroll
    for (int kvf = 0; kvf < 4; ++kvf)
      #pragma unroll
      for (int rp = 0; rp < 2; ++rp) {
        bf16x2 pv = {(bf16)exp2_fast(s[kvf][2 * rp]),
                     (bf16)exp2_fast(s[kvf][2 * rp + 1])};
        *(bf16x2*)(pl + l15 * 72 + kvf * 16 + l4 * 4 + 2 * rp) = pv;
      }
    // PV + denominator
    #pragma unroll
    for (int ss = 0; ss < 2; ++ss) {
      bf16x8 pf = *(const bf16x8*)(pl + l15 * 72 + ss * 32 + l4 * 8);
      accS = __builtin_amdgcn_mfma_f32_16x16x32_bf16(pf, vones, accS, 0, 0, 0);
      #pragma unroll
      for (int df = 0; df < 4; ++df) {
        bf16x8 vf = *(const bf16x8*)(Vp + (size_t)(df * 16 + l15) * 2048 + kv0 + ss * 32 + l4 * 8);
        accO[df] = __builtin_amdgcn_mfma_f32_16x16x32_bf16(pf, vf, accO[df], 0, 0, 0);
      }
    }
  }
  // finalize: O = accO / rowsum; accS[r] already holds the q-row sum in
  // every lane (all-ones B makes all 16 output cols equal). Write [B,N,C].
  #pragma unroll
  for (int r = 0; r < 4; ++r) {
    const float inv = 1.f / accS[r];
    const size_t orow = ((size_t)b * 2048 + q0 + l4 * 4 + r) * 1024 + h * 64;
    #pragma unroll
    for (int df = 0; df < 4; ++df)
      ao[orow + df * 16 + l15] = (bf16)(accO[df][r] * inv);
  }
}

// --------------------------------------------------------------------------
extern "C" void kernel_launch(void* const* d_in, const int* in_sizes, int n_in,
                              void* d_out, int out_size, void* d_ws, size_t ws_size,
                              hipStream_t stream)
{
  (void)in_sizes; (void)n_in; (void)out_size; (void)ws_size;
  const float* x      = (const float*)d_in[0];   // [2,2048,1024]
  const float* qkv_w  = (const float*)d_in[1];   // [3072,1024]
  const float* temp   = (const float*)d_in[2];   // [16,1,1]
  const float* proj_w = (const float*)d_in[3];   // [1024,1024]
  const float* proj_b = (const float*)d_in[4];   // [1024]
  float* out = (float*)d_out;                    // [2,2048,1024] fp32

  char* w = (char*)d_ws;
  auto take = [&](size_t bytes) { char* p = w; w += (bytes + 255) & ~(size_t)255; return p; };
  bf16*  xb    = (bf16*)take((size_t)4096 * 1024 * 2);   // x bf16
  bf16*  wqkvb = (bf16*)take((size_t)3072 * 1024 * 2);   // qkv_w bf16
  bf16*  wpb   = (bf16*)take((size_t)1024 * 1024 * 2);   // proj_w bf16
  bf16*  qkvb  = (bf16*)take((size_t)4096 * 3072 * 2);   // qkv out bf16
  float* invq  = (float*)take((size_t)4096 * 4);
  float* invk  = (float*)take((size_t)4096 * 4);
  bf16*  Qh    = (bf16*)take((size_t)32 * 2048 * 64 * 2);
  bf16*  Kh    = (bf16*)take((size_t)32 * 2048 * 64 * 2);
  bf16*  Vt    = (bf16*)take((size_t)32 * 64 * 2048 * 2);
  bf16*  ao    = (bf16*)take((size_t)4096 * 1024 * 2);

  k_cvt<<<4096, 256, 0, stream>>>(x, xb);
  k_cvt<<<3072, 256, 0, stream>>>(qkv_w, wqkvb);
  k_cvt<<<1024, 256, 0, stream>>>(proj_w, wpb);
  k_gemm_bt<1, 0><<<dim3(32, 24), 256, 0, stream>>>(xb, wqkvb, nullptr, qkvb, 1024, 3072);
  k_rownorm<<<1024, 256, 0, stream>>>(qkvb, invq, invk);
  k_scatter<<<dim3(32, 16, 2), 256, 0, stream>>>(qkvb, invq, invk, temp, Qh, Kh, Vt);
  k_attn<<<dim3(32, 16, 2), 256, 0, stream>>>(Qh, Kh, Vt, ao);
  k_gemm_bt<0, 1><<<dim3(32, 8), 256, 0, stream>>>(ao, wpb, proj_b, out, 1024, 1024);
}

// Round 6
// 214.535 us; speedup vs baseline: 1.8121x; 1.7975x over previous
//
#include <hip/hip_runtime.h>

typedef __bf16 bf16;
using bf16x2 = __attribute__((ext_vector_type(2))) bf16;
using bf16x4 = __attribute__((ext_vector_type(4))) bf16;
using bf16x8 = __attribute__((ext_vector_type(8))) bf16;
using f32x4  = __attribute__((ext_vector_type(4))) float;

#define DEVI __device__ __forceinline__

DEVI void gload_lds16(const void* g, void* l) {
  __builtin_amdgcn_global_load_lds((const __attribute__((address_space(1))) void*)g,
                                   (__attribute__((address_space(3))) void*)l, 16, 0, 0);
}

DEVI float exp2_fast(float x) { return __builtin_amdgcn_exp2f(x); }  // v_exp_f32

// ---------------- fp32 -> bf16 convert (4 elems/thread, exact grids) ------
__global__ __launch_bounds__(256) void k_cvt(const float* __restrict__ in,
                                             bf16* __restrict__ out) {
  int i = blockIdx.x * 256 + threadIdx.x;
  f32x4 v = ((const f32x4*)in)[i];
  bf16x4 o = {(bf16)v.x, (bf16)v.y, (bf16)v.z, (bf16)v.w};
  ((bf16x4*)out)[i] = o;
}

// ---------------- GEMM: out[m,n] = sum_k A[m,k]*W[n,k] (+bias) ------------
// 128x128 tile, BK=32, 4 waves (2x2 of 64x64), global_load_lds width=16.
template<int OUT_BF16, int HAS_BIAS>
__global__ __launch_bounds__(256) void k_gemm_bt(
    const bf16* __restrict__ A, const bf16* __restrict__ W,
    const float* __restrict__ bias, void* __restrict__ outp,
    int Kk, int Nout)
{
  __shared__ __align__(16) bf16 As[128 * 32];
  __shared__ __align__(16) bf16 Bs[128 * 32];
  const int t = threadIdx.x;
  const int lane = t & 63, wv = t >> 6;
  const int l15 = lane & 15, l4 = lane >> 4;
  const int row0 = blockIdx.x * 128, col0 = blockIdx.y * 128;
  const int wr = wv >> 1, wc = wv & 1;

  f32x4 acc[4][4];
  #pragma unroll
  for (int m = 0; m < 4; ++m)
    #pragma unroll
    for (int n = 0; n < 4; ++n) acc[m][n] = (f32x4){0.f, 0.f, 0.f, 0.f};

  // staging: 512 chunks of 16B per 128x32 tile; thread t owns chunks t, t+256
  const int g0 = t, g1 = t + 256;
  const bf16* ga0 = A + (size_t)(row0 + (g0 >> 2)) * Kk + (g0 & 3) * 8;
  const bf16* ga1 = A + (size_t)(row0 + (g1 >> 2)) * Kk + (g1 & 3) * 8;
  const bf16* gb0 = W + (size_t)(col0 + (g0 >> 2)) * Kk + (g0 & 3) * 8;
  const bf16* gb1 = W + (size_t)(col0 + (g1 >> 2)) * Kk + (g1 & 3) * 8;
  // wave-uniform LDS bases (lane*16 is added by HW)
  char* la0 = (char*)As + wv * 1024;
  char* la1 = (char*)As + 4096 + wv * 1024;
  char* lb0 = (char*)Bs + wv * 1024;
  char* lb1 = (char*)Bs + 4096 + wv * 1024;

  const int nk = Kk >> 5;
  for (int kt = 0; kt < nk; ++kt) {
    __syncthreads();
    gload_lds16(ga0 + kt * 32, la0);
    gload_lds16(ga1 + kt * 32, la1);
    gload_lds16(gb0 + kt * 32, lb0);
    gload_lds16(gb1 + kt * 32, lb1);
    __syncthreads();
    bf16x8 af[4], bfv[4];
    #pragma unroll
    for (int m = 0; m < 4; ++m)
      af[m] = *(const bf16x8*)(As + (wr * 64 + m * 16 + l15) * 32 + l4 * 8);
    #pragma unroll
    for (int n = 0; n < 4; ++n)
      bfv[n] = *(const bf16x8*)(Bs + (wc * 64 + n * 16 + l15) * 32 + l4 * 8);
    #pragma unroll
    for (int m = 0; m < 4; ++m)
      #pragma unroll
      for (int n = 0; n < 4; ++n)
        acc[m][n] = __builtin_amdgcn_mfma_f32_16x16x32_bf16(af[m], bfv[n], acc[m][n], 0, 0, 0);
  }

  // epilogue: D[row=(l>>4)*4+r][col=l&15] (m89-verified mapping)
  #pragma unroll
  for (int n = 0; n < 4; ++n) {
    const int col = col0 + wc * 64 + n * 16 + l15;
    float bv = HAS_BIAS ? bias[col] : 0.f;
    #pragma unroll
    for (int m = 0; m < 4; ++m) {
      #pragma unroll
      for (int r = 0; r < 4; ++r) {
        const int row = row0 + wr * 64 + m * 16 + l4 * 4 + r;
        float v = acc[m][n][r] + bv;
        if (OUT_BF16) ((bf16*)outp)[(size_t)row * Nout + col] = (bf16)v;
        else          ((float*)outp)[(size_t)row * Nout + col] = v;
      }
    }
  }
}

// ---------------- per-row L2 norm of q and k (one wave per row) -----------
__global__ __launch_bounds__(256) void k_rownorm(const bf16* __restrict__ qkv,
                                                 float* __restrict__ invq,
                                                 float* __restrict__ invk)
{
  const int row = blockIdx.x * 4 + (threadIdx.x >> 6);
  const int lane = threadIdx.x & 63;
  const bf16* p = qkv + (size_t)row * 3072 + lane * 16;
  float sq = 0.f, sk = 0.f;
  bf16x8 a0 = *(const bf16x8*)(p);
  bf16x8 a1 = *(const bf16x8*)(p + 8);
  bf16x8 b0 = *(const bf16x8*)(p + 1024);
  bf16x8 b1 = *(const bf16x8*)(p + 1032);
  #pragma unroll
  for (int j = 0; j < 8; ++j) {
    float x0 = (float)a0[j], x1 = (float)a1[j];
    float y0 = (float)b0[j], y1 = (float)b1[j];
    sq += x0 * x0 + x1 * x1;
    sk += y0 * y0 + y1 * y1;
  }
  #pragma unroll
  for (int m = 1; m <= 32; m <<= 1) {
    sq += __shfl_xor(sq, m);
    sk += __shfl_xor(sk, m);
  }
  if (lane == 0) {
    invq[row] = 0.125f / fmaxf(sqrtf(sq), 1e-12f);   // scale/max(||q||,eps)
    invk[row] = 0.125f / fmaxf(sqrtf(sk), 1e-12f);
  }
}

// ---------------- head split + normalize + V transpose --------------------
// Qh: [B,H,N,64] = q_hat*0.125
// Kh: [B,H,N,64] = k_hat*0.125*log2(e)/T[h]   (so QK^T is exp2-ready)
// Vt: [B,H,64,N]
__global__ __launch_bounds__(256) void k_scatter(
    const bf16* __restrict__ qkv, const float* __restrict__ invq,
    const float* __restrict__ invk, const float* __restrict__ temperature,
    bf16* __restrict__ Qh, bf16* __restrict__ Kh, bf16* __restrict__ Vt)
{
  __shared__ __align__(16) bf16 vt[64][72];
  const int t = threadIdx.x;
  const int b = blockIdx.z, h = blockIdx.y;
  const int n0 = blockIdx.x * 64;
  const float tfac = 1.4426950408889634f / temperature[h];  // log2(e)/T
  {
    const int nl = t >> 2;
    const int d0 = (t & 3) << 4;
    const size_t row = (size_t)b * 2048 + n0 + nl;
    const bf16* src = qkv + row * 3072 + h * 64 + d0;
    const float fq = invq[row];
    const float fk = invk[row] * tfac;
    bf16x8 q0 = *(const bf16x8*)(src);
    bf16x8 q1 = *(const bf16x8*)(src + 8);
    bf16x8 k0 = *(const bf16x8*)(src + 1024);
    bf16x8 k1 = *(const bf16x8*)(src + 1032);
    bf16x8 v0 = *(const bf16x8*)(src + 2048);
    bf16x8 v1 = *(const bf16x8*)(src + 2056);
    bf16x8 qo, ko;
    #pragma unroll
    for (int j = 0; j < 8; ++j) {
      qo[j] = (bf16)((float)q0[j] * fq);
      ko[j] = (bf16)((float)k0[j] * fk);
    }
    size_t orow = ((size_t)(b * 16 + h) * 2048 + n0 + nl) * 64 + d0;
    *(bf16x8*)(Qh + orow) = qo;
    *(bf16x8*)(Kh + orow) = ko;
    #pragma unroll
    for (int j = 0; j < 8; ++j) {
      qo[j] = (bf16)((float)q1[j] * fq);
      ko[j] = (bf16)((float)k1[j] * fk);
    }
    *(bf16x8*)(Qh + orow + 8) = qo;
    *(bf16x8*)(Kh + orow + 8) = ko;
    *(bf16x8*)&vt[nl][d0] = v0;
    *(bf16x8*)&vt[nl][d0 + 8] = v1;
  }
  __syncthreads();
  {
    const int d = t >> 2;
    const int nc = (t & 3) << 4;
    bf16x8 o0, o1;
    #pragma unroll
    for (int j = 0; j < 8; ++j) { o0[j] = vt[nc + j][d]; o1[j] = vt[nc + 8 + j][d]; }
    size_t obase = ((size_t)(b * 16 + h) * 64 + d) * 2048 + n0 + nc;
    *(bf16x8*)(Vt + obase) = o0;
    *(bf16x8*)(Vt + obase + 8) = o1;
  }
}

// ---------------- flash attention, LDS-staged K/V + prefetch ---------------
// 2-phase pipeline: per kv-tile (64), the block cooperatively stages the NEXT
// K/V tiles into LDS (global_load_lds, dbuf) BEFORE computing the current one
// -> HBM/L2 latency hides under compute; __syncthreads (vmcnt drain) at end.
// All 4 waves share the staged tiles (4x less VMEM than per-wave loads).
// XOR slot-swizzle (slot = chunk ^ (row&7)) applied via pre-swizzled global
// source + swizzled ds_read (rule: both-sides-or-neither) -> conflict-free
// b128 fragment reads. Max-free softmax as before (|S| small by construction,
// denominator via all-ones MFMA). Grid: 1D 1024, bijective XCD chunking
// (1024 = 8*128) so each XCD's L2 holds only 4 (b,h) planes of K/V.
__global__ __launch_bounds__(256) void k_attn(
    const bf16* __restrict__ Qh, const bf16* __restrict__ Kh,
    const bf16* __restrict__ Vt, bf16* __restrict__ ao)
{
  __shared__ __align__(16) bf16 Kb[2][64 * 64];   // [kv][d], swizzled slots
  __shared__ __align__(16) bf16 Vb[2][64 * 64];   // [d][kv], swizzled slots
  __shared__ __align__(16) bf16 Pl[4][16 * 64];   // per-wave P, swizzled
  const int t = threadIdx.x, lane = t & 63, wv = t >> 6;
  const int l15 = lane & 15, l4 = lane >> 4;

  const int bid = blockIdx.x;                       // 0..1023
  const int swz = (bid & 7) * 128 + (bid >> 3);     // XCD-chunked, bijective
  const int plane_id = swz >> 5;                    // b*16+h
  const int qb = swz & 31;
  const int b = plane_id >> 4, h = plane_id & 15;
  const int q0 = qb * 64 + wv * 16;

  const size_t plane = (size_t)plane_id * (2048 * 64);
  const bf16* Qp = Qh + plane;
  const bf16* Kp = Kh + plane;
  const bf16* Vp = Vt + plane;

  // staging lane geometry: 1KB chunk = 8 rows x 128B; row-in-chunk sr,
  // slot (lane&7) receives global 16B-chunk sc = (lane&7) ^ sr.
  const int sr = lane >> 3;
  const int sc = (lane & 7) ^ sr;
  const int j0 = wv * 2, j1 = j0 + 1;
  // per-lane global bases (kv0 added per iteration)
  const bf16* gK0 = Kp + (size_t)(j0 * 8 + sr) * 64 + sc * 8;   // + kv0*64
  const bf16* gK1 = Kp + (size_t)(j1 * 8 + sr) * 64 + sc * 8;
  const bf16* gV0 = Vp + (size_t)(j0 * 8 + sr) * 2048 + sc * 8; // + kv0
  const bf16* gV1 = Vp + (size_t)(j1 * 8 + sr) * 2048 + sc * 8;

  bf16x8 qf0 = *(const bf16x8*)(Qp + (q0 + l15) * 64 + l4 * 8);
  bf16x8 qf1 = *(const bf16x8*)(Qp + (q0 + l15) * 64 + 32 + l4 * 8);

  bf16x8 vones;
  #pragma unroll
  for (int j = 0; j < 8; ++j) vones[j] = (bf16)1.0f;

  f32x4 accO[4];
  #pragma unroll
  for (int df = 0; df < 4; ++df) accO[df] = (f32x4){0.f, 0.f, 0.f, 0.f};
  f32x4 accS = (f32x4){0.f, 0.f, 0.f, 0.f};

  bf16* pw = &Pl[wv][0] + l15 * 64;       // this lane's P row base
  const int pxor = (l15 & 7) << 3;        // P swizzle (elems)

#define STAGE(bi, kv0_)                                                     \
  do {                                                                      \
    gload_lds16(gK0 + (size_t)(kv0_) * 64, (char*)&Kb[bi][0] + j0 * 1024);  \
    gload_lds16(gK1 + (size_t)(kv0_) * 64, (char*)&Kb[bi][0] + j1 * 1024);  \
    gload_lds16(gV0 + (kv0_),              (char*)&Vb[bi][0] + j0 * 1024);  \
    gload_lds16(gV1 + (kv0_),              (char*)&Vb[bi][0] + j1 * 1024);  \
  } while (0)

  STAGE(0, 0);
  __syncthreads();   // drains vmcnt: tile 0 resident

  int cur = 0;
  for (int kt = 0; kt < 32; ++kt) {
    if (kt < 31) STAGE(cur ^ 1, (kt + 1) * 64);   // prefetch overlaps compute

    const bf16* kb = &Kb[cur][0];
    const bf16* vb = &Vb[cur][0];

    // QK^T (swapped): S[kv=(l>>4)*4+r][q=l15]
    f32x4 s[4];
    #pragma unroll
    for (int kvf = 0; kvf < 4; ++kvf) {
      const int row = kvf * 16 + l15;
      const int r7 = row & 7;
      bf16x8 kf0 = *(const bf16x8*)(kb + row * 64 + ((l4 ^ r7) * 8));
      bf16x8 kf1 = *(const bf16x8*)(kb + row * 64 + (((4 + l4) ^ r7) * 8));
      s[kvf] = (f32x4){0.f, 0.f, 0.f, 0.f};
      s[kvf] = __builtin_amdgcn_mfma_f32_16x16x32_bf16(kf0, qf0, s[kvf], 0, 0, 0);
      s[kvf] = __builtin_amdgcn_mfma_f32_16x16x32_bf16(kf1, qf1, s[kvf], 0, 0, 0);
    }
    // P = exp2(S) -> bf16 pairs -> swizzled per-wave LDS row
    #pragma unroll
    for (int kvf = 0; kvf < 4; ++kvf)
      #pragma unroll
      for (int rp = 0; rp < 2; ++rp) {
        bf16x2 pv = {(bf16)exp2_fast(s[kvf][2 * rp]),
                     (bf16)exp2_fast(s[kvf][2 * rp + 1])};
        *(bf16x2*)(pw + ((kvf * 16 + l4 * 4 + 2 * rp) ^ pxor)) = pv;
      }
    // PV + denominator (A = P from LDS, B = V from LDS)
    #pragma unroll
    for (int ss = 0; ss < 2; ++ss) {
      bf16x8 pf = *(const bf16x8*)(pw + (((ss * 32 + l4 * 8)) ^ pxor));
      accS = __builtin_amdgcn_mfma_f32_16x16x32_bf16(pf, vones, accS, 0, 0, 0);
      #pragma unroll
      for (int df = 0; df < 4; ++df) {
        const int row = df * 16 + l15;
        bf16x8 vf = *(const bf16x8*)(vb + row * 64 + (((ss * 4 + l4) ^ (row & 7)) * 8));
        accO[df] = __builtin_amdgcn_mfma_f32_16x16x32_bf16(pf, vf, accO[df], 0, 0, 0);
      }
    }
    __syncthreads();   // readers done + prefetch drained (vmcnt 0)
    cur ^= 1;
  }
#undef STAGE

  // finalize: O = accO / rowsum; accS[r] holds the q-row sum in every lane.
  #pragma unroll
  for (int r = 0; r < 4; ++r) {
    const float inv = 1.f / accS[r];
    const size_t orow = ((size_t)b * 2048 + q0 + l4 * 4 + r) * 1024 + h * 64;
    #pragma unroll
    for (int df = 0; df < 4; ++df)
      ao[orow + df * 16 + l15] = (bf16)(accO[df][r] * inv);
  }
}

// --------------------------------------------------------------------------
extern "C" void kernel_launch(void* const* d_in, const int* in_sizes, int n_in,
                              void* d_out, int out_size, void* d_ws, size_t ws_size,
                              hipStream_t stream)
{
  (void)in_sizes; (void)n_in; (void)out_size; (void)ws_size;
  const float* x      = (const float*)d_in[0];   // [2,2048,1024]
  const float* qkv_w  = (const float*)d_in[1];   // [3072,1024]
  const float* temp   = (const float*)d_in[2];   // [16,1,1]
  const float* proj_w = (const float*)d_in[3];   // [1024,1024]
  const float* proj_b = (const float*)d_in[4];   // [1024]
  float* out = (float*)d_out;                    // [2,2048,1024] fp32

  char* w = (char*)d_ws;
  auto take = [&](size_t bytes) { char* p = w; w += (bytes + 255) & ~(size_t)255; return p; };
  bf16*  xb    = (bf16*)take((size_t)4096 * 1024 * 2);   // x bf16
  bf16*  wqkvb = (bf16*)take((size_t)3072 * 1024 * 2);   // qkv_w bf16
  bf16*  wpb   = (bf16*)take((size_t)1024 * 1024 * 2);   // proj_w bf16
  bf16*  qkvb  = (bf16*)take((size_t)4096 * 3072 * 2);   // qkv out bf16
  float* invq  = (float*)take((size_t)4096 * 4);
  float* invk  = (float*)take((size_t)4096 * 4);
  bf16*  Qh    = (bf16*)take((size_t)32 * 2048 * 64 * 2);
  bf16*  Kh    = (bf16*)take((size_t)32 * 2048 * 64 * 2);
  bf16*  Vt    = (bf16*)take((size_t)32 * 64 * 2048 * 2);
  bf16*  ao    = (bf16*)take((size_t)4096 * 1024 * 2);

  k_cvt<<<4096, 256, 0, stream>>>(x, xb);
  k_cvt<<<3072, 256, 0, stream>>>(qkv_w, wqkvb);
  k_cvt<<<1024, 256, 0, stream>>>(proj_w, wpb);
  k_gemm_bt<1, 0><<<dim3(32, 24), 256, 0, stream>>>(xb, wqkvb, nullptr, qkvb, 1024, 3072);
  k_rownorm<<<1024, 256, 0, stream>>>(qkvb, invq, invk);
  k_scatter<<<dim3(32, 16, 2), 256, 0, stream>>>(qkvb, invq, invk, temp, Qh, Kh, Vt);
  k_attn<<<1024, 256, 0, stream>>>(Qh, Kh, Vt, ao);
  k_gemm_bt<0, 1><<<dim3(32, 8), 256, 0, stream>>>(ao, wpb, proj_b, out, 1024, 1024);
}

// Round 7
// 203.780 us; speedup vs baseline: 1.9077x; 1.0528x over previous
//
#include <hip/hip_runtime.h>

typedef __bf16 bf16;
using bf16x2 = __attribute__((ext_vector_type(2))) bf16;
using bf16x4 = __attribute__((ext_vector_type(4))) bf16;
using bf16x8 = __attribute__((ext_vector_type(8))) bf16;
using f32x4  = __attribute__((ext_vector_type(4))) float;

#define DEVI __device__ __forceinline__

DEVI void gload_lds16(const void* g, void* l) {
  __builtin_amdgcn_global_load_lds((const __attribute__((address_space(1))) void*)g,
                                   (__attribute__((address_space(3))) void*)l, 16, 0, 0);
}

DEVI float exp2_fast(float x) { return __builtin_amdgcn_exp2f(x); }  // v_exp_f32

// ---------------- fp32 -> bf16 convert (4 elems/thread, exact grids) ------
__global__ __launch_bounds__(256) void k_cvt(const float* __restrict__ in,
                                             bf16* __restrict__ out) {
  int i = blockIdx.x * 256 + threadIdx.x;
  f32x4 v = ((const f32x4*)in)[i];
  bf16x4 o = {(bf16)v.x, (bf16)v.y, (bf16)v.z, (bf16)v.w};
  ((bf16x4*)out)[i] = o;
}

// ---------------- GEMM: out[m,n] = sum_k A[m,k]*W[n,k] (+bias) ------------
// 128x128 tile, BK=32, 4 waves (2x2 of 64x64), global_load_lds width=16.
template<int OUT_BF16, int HAS_BIAS>
__global__ __launch_bounds__(256) void k_gemm_bt(
    const bf16* __restrict__ A, const bf16* __restrict__ W,
    const float* __restrict__ bias, void* __restrict__ outp,
    int Kk, int Nout)
{
  __shared__ __align__(16) bf16 As[128 * 32];
  __shared__ __align__(16) bf16 Bs[128 * 32];
  const int t = threadIdx.x;
  const int lane = t & 63, wv = t >> 6;
  const int l15 = lane & 15, l4 = lane >> 4;
  const int row0 = blockIdx.x * 128, col0 = blockIdx.y * 128;
  const int wr = wv >> 1, wc = wv & 1;

  f32x4 acc[4][4];
  #pragma unroll
  for (int m = 0; m < 4; ++m)
    #pragma unroll
    for (int n = 0; n < 4; ++n) acc[m][n] = (f32x4){0.f, 0.f, 0.f, 0.f};

  // staging: 512 chunks of 16B per 128x32 tile; thread t owns chunks t, t+256
  const int g0 = t, g1 = t + 256;
  const bf16* ga0 = A + (size_t)(row0 + (g0 >> 2)) * Kk + (g0 & 3) * 8;
  const bf16* ga1 = A + (size_t)(row0 + (g1 >> 2)) * Kk + (g1 & 3) * 8;
  const bf16* gb0 = W + (size_t)(col0 + (g0 >> 2)) * Kk + (g0 & 3) * 8;
  const bf16* gb1 = W + (size_t)(col0 + (g1 >> 2)) * Kk + (g1 & 3) * 8;
  // wave-uniform LDS bases (lane*16 is added by HW)
  char* la0 = (char*)As + wv * 1024;
  char* la1 = (char*)As + 4096 + wv * 1024;
  char* lb0 = (char*)Bs + wv * 1024;
  char* lb1 = (char*)Bs + 4096 + wv * 1024;

  const int nk = Kk >> 5;
  for (int kt = 0; kt < nk; ++kt) {
    __syncthreads();
    gload_lds16(ga0 + kt * 32, la0);
    gload_lds16(ga1 + kt * 32, la1);
    gload_lds16(gb0 + kt * 32, lb0);
    gload_lds16(gb1 + kt * 32, lb1);
    __syncthreads();
    bf16x8 af[4], bfv[4];
    #pragma unroll
    for (int m = 0; m < 4; ++m)
      af[m] = *(const bf16x8*)(As + (wr * 64 + m * 16 + l15) * 32 + l4 * 8);
    #pragma unroll
    for (int n = 0; n < 4; ++n)
      bfv[n] = *(const bf16x8*)(Bs + (wc * 64 + n * 16 + l15) * 32 + l4 * 8);
    #pragma unroll
    for (int m = 0; m < 4; ++m)
      #pragma unroll
      for (int n = 0; n < 4; ++n)
        acc[m][n] = __builtin_amdgcn_mfma_f32_16x16x32_bf16(af[m], bfv[n], acc[m][n], 0, 0, 0);
  }

  // epilogue: D[row=(l>>4)*4+r][col=l&15] (m89-verified mapping)
  #pragma unroll
  for (int n = 0; n < 4; ++n) {
    const int col = col0 + wc * 64 + n * 16 + l15;
    float bv = HAS_BIAS ? bias[col] : 0.f;
    #pragma unroll
    for (int m = 0; m < 4; ++m) {
      #pragma unroll
      for (int r = 0; r < 4; ++r) {
        const int row = row0 + wr * 64 + m * 16 + l4 * 4 + r;
        float v = acc[m][n][r] + bv;
        if (OUT_BF16) ((bf16*)outp)[(size_t)row * Nout + col] = (bf16)v;
        else          ((float*)outp)[(size_t)row * Nout + col] = v;
      }
    }
  }
}

// ---------------- per-row L2 norm of q and k (one wave per row) -----------
__global__ __launch_bounds__(256) void k_rownorm(const bf16* __restrict__ qkv,
                                                 float* __restrict__ invq,
                                                 float* __restrict__ invk)
{
  const int row = blockIdx.x * 4 + (threadIdx.x >> 6);
  const int lane = threadIdx.x & 63;
  const bf16* p = qkv + (size_t)row * 3072 + lane * 16;
  float sq = 0.f, sk = 0.f;
  bf16x8 a0 = *(const bf16x8*)(p);
  bf16x8 a1 = *(const bf16x8*)(p + 8);
  bf16x8 b0 = *(const bf16x8*)(p + 1024);
  bf16x8 b1 = *(const bf16x8*)(p + 1032);
  #pragma unroll
  for (int j = 0; j < 8; ++j) {
    float x0 = (float)a0[j], x1 = (float)a1[j];
    float y0 = (float)b0[j], y1 = (float)b1[j];
    sq += x0 * x0 + x1 * x1;
    sk += y0 * y0 + y1 * y1;
  }
  #pragma unroll
  for (int m = 1; m <= 32; m <<= 1) {
    sq += __shfl_xor(sq, m);
    sk += __shfl_xor(sk, m);
  }
  if (lane == 0) {
    invq[row] = 0.125f / fmaxf(sqrtf(sq), 1e-12f);   // scale/max(||q||,eps)
    invk[row] = 0.125f / fmaxf(sqrtf(sk), 1e-12f);
  }
}

// ---------------- head split + normalize + V transpose --------------------
// Qh: [B,H,N,64] = q_hat*0.125
// Kh: [B,H,N,64] = k_hat*0.125*log2(e)/T[h]   (so QK^T is exp2-ready)
// Vt: [B,H,64,N]
__global__ __launch_bounds__(256) void k_scatter(
    const bf16* __restrict__ qkv, const float* __restrict__ invq,
    const float* __restrict__ invk, const float* __restrict__ temperature,
    bf16* __restrict__ Qh, bf16* __restrict__ Kh, bf16* __restrict__ Vt)
{
  __shared__ __align__(16) bf16 vt[64][72];
  const int t = threadIdx.x;
  const int b = blockIdx.z, h = blockIdx.y;
  const int n0 = blockIdx.x * 64;
  const float tfac = 1.4426950408889634f / temperature[h];  // log2(e)/T
  {
    const int nl = t >> 2;
    const int d0 = (t & 3) << 4;
    const size_t row = (size_t)b * 2048 + n0 + nl;
    const bf16* src = qkv + row * 3072 + h * 64 + d0;
    const float fq = invq[row];
    const float fk = invk[row] * tfac;
    bf16x8 q0 = *(const bf16x8*)(src);
    bf16x8 q1 = *(const bf16x8*)(src + 8);
    bf16x8 k0 = *(const bf16x8*)(src + 1024);
    bf16x8 k1 = *(const bf16x8*)(src + 1032);
    bf16x8 v0 = *(const bf16x8*)(src + 2048);
    bf16x8 v1 = *(const bf16x8*)(src + 2056);
    bf16x8 qo, ko;
    #pragma unroll
    for (int j = 0; j < 8; ++j) {
      qo[j] = (bf16)((float)q0[j] * fq);
      ko[j] = (bf16)((float)k0[j] * fk);
    }
    size_t orow = ((size_t)(b * 16 + h) * 2048 + n0 + nl) * 64 + d0;
    *(bf16x8*)(Qh + orow) = qo;
    *(bf16x8*)(Kh + orow) = ko;
    #pragma unroll
    for (int j = 0; j < 8; ++j) {
      qo[j] = (bf16)((float)q1[j] * fq);
      ko[j] = (bf16)((float)k1[j] * fk);
    }
    *(bf16x8*)(Qh + orow + 8) = qo;
    *(bf16x8*)(Kh + orow + 8) = ko;
    *(bf16x8*)&vt[nl][d0] = v0;
    *(bf16x8*)&vt[nl][d0 + 8] = v1;
  }
  __syncthreads();
  {
    const int d = t >> 2;
    const int nc = (t & 3) << 4;
    bf16x8 o0, o1;
    #pragma unroll
    for (int j = 0; j < 8; ++j) { o0[j] = vt[nc + j][d]; o1[j] = vt[nc + 8 + j][d]; }
    size_t obase = ((size_t)(b * 16 + h) * 64 + d) * 2048 + n0 + nc;
    *(bf16x8*)(Vt + obase) = o0;
    *(bf16x8*)(Vt + obase + 8) = o1;
  }
}

// ---------------- flash attention, LDS-staged K/V + prefetch ---------------
// 512 threads / 8 waves per block; q-tile = 128 rows (16 per wave) sharing
// ONE staged K/V tile -> staging bytes per FLOP halved vs q-tile 64, and
// LDS per q-row drops: 48KB total but grid 512 -> 2 blocks/CU = 16 waves/CU
// (was 12). Same 2-phase pipeline: stage NEXT K/V (global_load_lds, dbuf)
// before computing current; one __syncthreads (vmcnt drain) per iter.
// XOR slot-swizzle on K/V (slot = chunk ^ (row&7)) via pre-swizzled global
// source + swizzled ds_read. Max-free softmax (|S| small by construction),
// denominator via all-ones MFMA. Grid 512 = 8 XCDs x 64: bijective chunking
// puts 4 (b,h) planes per XCD (K+V = 2MB, fits 4MB L2).
__global__ __launch_bounds__(512, 4) void k_attn(
    const bf16* __restrict__ Qh, const bf16* __restrict__ Kh,
    const bf16* __restrict__ Vt, bf16* __restrict__ ao)
{
  __shared__ __align__(16) bf16 Kb[2][64 * 64];   // [kv][d], swizzled slots
  __shared__ __align__(16) bf16 Vb[2][64 * 64];   // [d][kv], swizzled slots
  __shared__ __align__(16) bf16 Pl[8][16 * 64];   // per-wave P, swizzled
  const int t = threadIdx.x, lane = t & 63, wv = t >> 6;
  const int l15 = lane & 15, l4 = lane >> 4;

  const int bid = blockIdx.x;                       // 0..511
  const int swz = (bid & 7) * 64 + (bid >> 3);      // XCD-chunked, bijective
  const int plane_id = swz >> 4;                    // b*16+h
  const int qb = swz & 15;
  const int b = plane_id >> 4, h = plane_id & 15;
  const int q0 = qb * 128 + wv * 16;

  const size_t plane = (size_t)plane_id * (2048 * 64);
  const bf16* Qp = Qh + plane;
  const bf16* Kp = Kh + plane;
  const bf16* Vp = Vt + plane;

  // staging: thread t owns 16B chunk t of each 8KB tile (64 rows x 128B).
  // row = t>>3, slot = t&7; slot holds global chunk sc = slot ^ (row&7).
  const int srow = t >> 3;
  const int sc = (t & 7) ^ (srow & 7);
  const bf16* gK = Kp + (size_t)srow * 64 + sc * 8;     // + kv0*64
  const bf16* gV = Vp + (size_t)srow * 2048 + sc * 8;   // + kv0
  char* lK0 = (char*)&Kb[0][0] + wv * 1024;             // lane*16 added by HW
  char* lK1 = (char*)&Kb[1][0] + wv * 1024;
  char* lV0 = (char*)&Vb[0][0] + wv * 1024;
  char* lV1 = (char*)&Vb[1][0] + wv * 1024;

  bf16x8 qf0 = *(const bf16x8*)(Qp + (q0 + l15) * 64 + l4 * 8);
  bf16x8 qf1 = *(const bf16x8*)(Qp + (q0 + l15) * 64 + 32 + l4 * 8);

  bf16x8 vones;
  #pragma unroll
  for (int j = 0; j < 8; ++j) vones[j] = (bf16)1.0f;

  f32x4 accO[4];
  #pragma unroll
  for (int df = 0; df < 4; ++df) accO[df] = (f32x4){0.f, 0.f, 0.f, 0.f};
  f32x4 accS = (f32x4){0.f, 0.f, 0.f, 0.f};

  bf16* pw = &Pl[wv][0] + l15 * 64;       // this lane's P row base
  const int pxor = (l15 & 7) << 3;        // P swizzle (elems)

#define STAGE(bi, kv0_)                                           \
  do {                                                            \
    gload_lds16(gK + (size_t)(kv0_) * 64, (bi) ? lK1 : lK0);      \
    gload_lds16(gV + (kv0_),              (bi) ? lV1 : lV0);      \
  } while (0)

  STAGE(0, 0);
  __syncthreads();   // drains vmcnt: tile 0 resident

  int cur = 0;
  for (int kt = 0; kt < 32; ++kt) {
    if (kt < 31) STAGE(cur ^ 1, (kt + 1) * 64);   // prefetch overlaps compute

    const bf16* kb = &Kb[cur][0];
    const bf16* vb = &Vb[cur][0];

    // QK^T (swapped): S[kv=(l>>4)*4+r][q=l15]
    f32x4 s[4];
    #pragma unroll
    for (int kvf = 0; kvf < 4; ++kvf) {
      const int row = kvf * 16 + l15;
      const int r7 = row & 7;
      bf16x8 kf0 = *(const bf16x8*)(kb + row * 64 + ((l4 ^ r7) * 8));
      bf16x8 kf1 = *(const bf16x8*)(kb + row * 64 + (((4 + l4) ^ r7) * 8));
      s[kvf] = (f32x4){0.f, 0.f, 0.f, 0.f};
      s[kvf] = __builtin_amdgcn_mfma_f32_16x16x32_bf16(kf0, qf0, s[kvf], 0, 0, 0);
      s[kvf] = __builtin_amdgcn_mfma_f32_16x16x32_bf16(kf1, qf1, s[kvf], 0, 0, 0);
    }
    // P = exp2(S) -> bf16 pairs -> swizzled per-wave LDS row
    #pragma unroll
    for (int kvf = 0; kvf < 4; ++kvf)
      #pragma unroll
      for (int rp = 0; rp < 2; ++rp) {
        bf16x2 pv = {(bf16)exp2_fast(s[kvf][2 * rp]),
                     (bf16)exp2_fast(s[kvf][2 * rp + 1])};
        *(bf16x2*)(pw + ((kvf * 16 + l4 * 4 + 2 * rp) ^ pxor)) = pv;
      }
    // PV + denominator (A = P from LDS, B = V from LDS)
    #pragma unroll
    for (int ss = 0; ss < 2; ++ss) {
      bf16x8 pf = *(const bf16x8*)(pw + (((ss * 32 + l4 * 8)) ^ pxor));
      accS = __builtin_amdgcn_mfma_f32_16x16x32_bf16(pf, vones, accS, 0, 0, 0);
      #pragma unroll
      for (int df = 0; df < 4; ++df) {
        const int row = df * 16 + l15;
        bf16x8 vf = *(const bf16x8*)(vb + row * 64 + (((ss * 4 + l4) ^ (row & 7)) * 8));
        accO[df] = __builtin_amdgcn_mfma_f32_16x16x32_bf16(pf, vf, accO[df], 0, 0, 0);
      }
    }
    __syncthreads();   // readers done + prefetch drained (vmcnt 0)
    cur ^= 1;
  }
#undef STAGE

  // finalize: O = accO / rowsum; accS[r] holds the q-row sum in every lane.
  #pragma unroll
  for (int r = 0; r < 4; ++r) {
    const float inv = 1.f / accS[r];
    const size_t orow = ((size_t)b * 2048 + q0 + l4 * 4 + r) * 1024 + h * 64;
    #pragma unroll
    for (int df = 0; df < 4; ++df)
      ao[orow + df * 16 + l15] = (bf16)(accO[df][r] * inv);
  }
}

// --------------------------------------------------------------------------
extern "C" void kernel_launch(void* const* d_in, const int* in_sizes, int n_in,
                              void* d_out, int out_size, void* d_ws, size_t ws_size,
                              hipStream_t stream)
{
  (void)in_sizes; (void)n_in; (void)out_size; (void)ws_size;
  const float* x      = (const float*)d_in[0];   // [2,2048,1024]
  const float* qkv_w  = (const float*)d_in[1];   // [3072,1024]
  const float* temp   = (const float*)d_in[2];   // [16,1,1]
  const float* proj_w = (const float*)d_in[3];   // [1024,1024]
  const float* proj_b = (const float*)d_in[4];   // [1024]
  float* out = (float*)d_out;                    // [2,2048,1024] fp32

  char* w = (char*)d_ws;
  auto take = [&](size_t bytes) { char* p = w; w += (bytes + 255) & ~(size_t)255; return p; };
  bf16*  xb    = (bf16*)take((size_t)4096 * 1024 * 2);   // x bf16
  bf16*  wqkvb = (bf16*)take((size_t)3072 * 1024 * 2);   // qkv_w bf16
  bf16*  wpb   = (bf16*)take((size_t)1024 * 1024 * 2);   // proj_w bf16
  bf16*  qkvb  = (bf16*)take((size_t)4096 * 3072 * 2);   // qkv out bf16
  float* invq  = (float*)take((size_t)4096 * 4);
  float* invk  = (float*)take((size_t)4096 * 4);
  bf16*  Qh    = (bf16*)take((size_t)32 * 2048 * 64 * 2);
  bf16*  Kh    = (bf16*)take((size_t)32 * 2048 * 64 * 2);
  bf16*  Vt    = (bf16*)take((size_t)32 * 64 * 2048 * 2);
  bf16*  ao    = (bf16*)take((size_t)4096 * 1024 * 2);

  k_cvt<<<4096, 256, 0, stream>>>(x, xb);
  k_cvt<<<3072, 256, 0, stream>>>(qkv_w, wqkvb);
  k_cvt<<<1024, 256, 0, stream>>>(proj_w, wpb);
  k_gemm_bt<1, 0><<<dim3(32, 24), 256, 0, stream>>>(xb, wqkvb, nullptr, qkvb, 1024, 3072);
  k_rownorm<<<1024, 256, 0, stream>>>(qkvb, invq, invk);
  k_scatter<<<dim3(32, 16, 2), 256, 0, stream>>>(qkvb, invq, invk, temp, Qh, Kh, Vt);
  k_attn<<<512, 512, 0, stream>>>(Qh, Kh, Vt, ao);
  k_gemm_bt<0, 1><<<dim3(32, 8), 256, 0, stream>>>(ao, wpb, proj_b, out, 1024, 1024);
}